// Round 2
// baseline (229.722 us; speedup 1.0000x reference)
//
#include <hip/hip_runtime.h>

// out = sign * FWHT(x), x: 16384 x 2048 fp32; scale 2^-5.5 applied once at
// the end; sign = -1 for n >= 1536.
//
// One WAVE (64 lanes) per row; 32 elements/lane. Lane i owns
// n = 256k + 4i + e  (k=0..7, e=0..3):
//   - bits 0,1   : inside each float4 (register butterflies)
//   - bits 8,9,10: across the 8 float4s k (register butterflies)
//   - bits 2..7  : lane XOR {1,2,4,8,16,32} via __shfl_xor (no LDS storage,
//                  no __syncthreads, no barriers at all)
// Butterfly via one FMA: v_new = w + s*v, s = (lane&m) ? -1 : +1.
// 8 coalesced dwordx4 loads + 8 coalesced dwordx4 stores per lane.

#define NN 2048

__global__ __launch_bounds__(256) void fwht_sign_kernel(const float* __restrict__ x,
                                                        float* __restrict__ out) {
    const int lane = threadIdx.x & 63;
    const int wid  = threadIdx.x >> 6;
    const long long row = (long long)blockIdx.x * 4 + wid;
    const float* __restrict__ xr  = x   + row * (long long)NN;
    float* __restrict__       outr = out + row * (long long)NN;

    float v[8][4];

    // ---- load: 8 coalesced float4s ----
#pragma unroll
    for (int k = 0; k < 8; ++k) {
        const float4 t = *reinterpret_cast<const float4*>(xr + 256 * k + 4 * lane);
        v[k][0] = t.x; v[k][1] = t.y; v[k][2] = t.z; v[k][3] = t.w;
    }

    // ---- bits 0,1: inside each float4 ----
#pragma unroll
    for (int k = 0; k < 8; ++k) {
        float a0 = v[k][0], a1 = v[k][1], a2 = v[k][2], a3 = v[k][3];
        // bit 0 (stride 1)
        float b0 = a0 + a1, b1 = a0 - a1, b2 = a2 + a3, b3 = a2 - a3;
        // bit 1 (stride 2)
        v[k][0] = b0 + b2; v[k][1] = b1 + b3;
        v[k][2] = b0 - b2; v[k][3] = b1 - b3;
    }

    // ---- bits 8,9,10: across k with k-strides 1,2,4 ----
#pragma unroll
    for (int e = 0; e < 4; ++e) {
        // k XOR 1
#pragma unroll
        for (int k = 0; k < 8; k += 2) {
            float a = v[k][e], b = v[k + 1][e];
            v[k][e] = a + b; v[k + 1][e] = a - b;
        }
        // k XOR 2
#pragma unroll
        for (int k = 0; k < 8; k += 4) {
            float a0 = v[k][e], a1 = v[k + 1][e], b0 = v[k + 2][e], b1 = v[k + 3][e];
            v[k][e] = a0 + b0; v[k + 1][e] = a1 + b1;
            v[k + 2][e] = a0 - b0; v[k + 3][e] = a1 - b1;
        }
        // k XOR 4
#pragma unroll
        for (int k = 0; k < 4; ++k) {
            float a = v[k][e], b = v[k + 4][e];
            v[k][e] = a + b; v[k + 4][e] = a - b;
        }
    }

    // ---- bits 2..7: cross-lane butterflies, lane XOR m ----
#pragma unroll
    for (int s = 0; s < 6; ++s) {
        const int m = 1 << s;
        const float sg = (lane & m) ? -1.0f : 1.0f;
#pragma unroll
        for (int k = 0; k < 8; ++k) {
#pragma unroll
            for (int e = 0; e < 4; ++e) {
                const float w = __shfl_xor(v[k][e], m, 64);
                v[k][e] = fmaf(sg, v[k][e], w);
            }
        }
    }

    // ---- scale + sign + store: n >= 1536 <=> k >= 6 ----
    const float M = 0.022097086912079608f;  // 2^-5.5
#pragma unroll
    for (int k = 0; k < 8; ++k) {
        const float mk = (k >= 6) ? -M : M;
        float4 t;
        t.x = v[k][0] * mk; t.y = v[k][1] * mk;
        t.z = v[k][2] * mk; t.w = v[k][3] * mk;
        *reinterpret_cast<float4*>(outr + 256 * k + 4 * lane) = t;
    }
}

extern "C" void kernel_launch(void* const* d_in, const int* in_sizes, int n_in,
                              void* d_out, int out_size, void* d_ws, size_t ws_size,
                              hipStream_t stream) {
    const float* x = (const float*)d_in[0];
    float* out = (float*)d_out;
    const int rows = in_sizes[0] / NN;            // 16384
    fwht_sign_kernel<<<dim3(rows / 4), dim3(256), 0, stream>>>(x, out);
}

// Round 3
// 220.140 us; speedup vs baseline: 1.0435x; 1.0435x over previous
//
#include <hip/hip_runtime.h>

// out = sign * FWHT(x), x: 16384 x 2048 fp32; scale 2^-5.5 fused; sign = -1
// for n >= 1536 (n10&n9).
//
// One wave per row, 32 elements/lane: v[k][e], n = (k2 k1 k0 | l5..l0 | e1 e0).
// Stages (all commute):
//   bits 0,1   : register butterflies inside each float4
//   bits 8,9,10: register butterflies across k
//   bits 2,3   : lane xor 1,2 -> DPP quad_perm (pure VALU)
//   bits 4,5   : lane xor 4,8 -> ds_swizzle (only 2 DS-pipe stages)
//   bit  7     : v_permlane32_swap (lane-bit5 <-> pair-bit k0), then reg butterfly
//   bit  6     : v_permlane16_swap (lane-bit4 <-> pair-bit),   then reg butterfly
// Final layout: n = k2*1024 + k1*512 + l5*256 + l4*128 + k0*64 + (l&15)*4 + e
// -> stores are 4x 256B contiguous chunks per wave instr (fully coalesced).

#define NN 2048

typedef float f4 __attribute__((ext_vector_type(4)));
typedef unsigned int v2u __attribute__((ext_vector_type(2)));

template <int CTRL>
__device__ __forceinline__ float dppf(float x) {
    return __int_as_float(__builtin_amdgcn_mov_dpp(__float_as_int(x), CTRL, 0xF, 0xF, true));
}

template <int MASK>
__device__ __forceinline__ float swzf(float x) {
    return __int_as_float(__builtin_amdgcn_ds_swizzle(__float_as_int(x), (MASK << 10) | 0x1F));
}

#if __has_builtin(__builtin_amdgcn_permlane32_swap)
#define HAVE_PLSWAP 1
__device__ __forceinline__ void pl32_swap(float& a, float& b) {
    v2u r = __builtin_amdgcn_permlane32_swap(__float_as_uint(a), __float_as_uint(b), false, false);
    a = __uint_as_float(r[0]);
    b = __uint_as_float(r[1]);
}
__device__ __forceinline__ void pl16_swap(float& a, float& b) {
    v2u r = __builtin_amdgcn_permlane16_swap(__float_as_uint(a), __float_as_uint(b), false, false);
    a = __uint_as_float(r[0]);
    b = __uint_as_float(r[1]);
}
#else
#define HAVE_PLSWAP 0
#endif

__global__ __launch_bounds__(256) void fwht_sign_kernel(const float* __restrict__ x,
                                                        float* __restrict__ out) {
    const int lane = threadIdx.x & 63;
    const int wid  = threadIdx.x >> 6;
    const long long row = (long long)blockIdx.x * 4 + wid;
    const float* __restrict__ xr   = x   + row * (long long)NN;
    float* __restrict__       outr = out + row * (long long)NN;

    float v[8][4];

    // ---- load: 8 coalesced nontemporal float4s ----
#pragma unroll
    for (int k = 0; k < 8; ++k) {
        const f4 t = __builtin_nontemporal_load(
            reinterpret_cast<const f4*>(xr + 256 * k + 4 * lane));
        v[k][0] = t[0]; v[k][1] = t[1]; v[k][2] = t[2]; v[k][3] = t[3];
    }

    // ---- bits 0,1 (e), per k ----
#pragma unroll
    for (int k = 0; k < 8; ++k) {
        float a0 = v[k][0], a1 = v[k][1], a2 = v[k][2], a3 = v[k][3];
        float b0 = a0 + a1, b1 = a0 - a1, b2 = a2 + a3, b3 = a2 - a3;
        v[k][0] = b0 + b2; v[k][1] = b1 + b3;
        v[k][2] = b0 - b2; v[k][3] = b1 - b3;
    }

    // ---- bits 8,9,10 (k) ----
#pragma unroll
    for (int e = 0; e < 4; ++e) {
#pragma unroll
        for (int k = 0; k < 8; k += 2) {
            float a = v[k][e], b = v[k + 1][e];
            v[k][e] = a + b; v[k + 1][e] = a - b;
        }
#pragma unroll
        for (int k = 0; k < 8; k += 4) {
            float a0 = v[k][e], a1 = v[k + 1][e], b0 = v[k + 2][e], b1 = v[k + 3][e];
            v[k][e] = a0 + b0; v[k + 1][e] = a1 + b1;
            v[k + 2][e] = a0 - b0; v[k + 3][e] = a1 - b1;
        }
#pragma unroll
        for (int k = 0; k < 4; ++k) {
            float a = v[k][e], b = v[k + 4][e];
            v[k][e] = a + b; v[k + 4][e] = a - b;
        }
    }

    // ---- bit 2: lane xor 1 via DPP quad_perm {1,0,3,2} = 0xB1 ----
    {
        const float s = (lane & 1) ? -1.0f : 1.0f;
#pragma unroll
        for (int k = 0; k < 8; ++k)
#pragma unroll
            for (int e = 0; e < 4; ++e) {
                const float w = dppf<0xB1>(v[k][e]);
                v[k][e] = fmaf(s, v[k][e], w);
            }
    }
    // ---- bit 3: lane xor 2 via DPP quad_perm {2,3,0,1} = 0x4E ----
    {
        const float s = (lane & 2) ? -1.0f : 1.0f;
#pragma unroll
        for (int k = 0; k < 8; ++k)
#pragma unroll
            for (int e = 0; e < 4; ++e) {
                const float w = dppf<0x4E>(v[k][e]);
                v[k][e] = fmaf(s, v[k][e], w);
            }
    }
    // ---- bit 4: lane xor 4 via ds_swizzle ----
    {
        const float s = (lane & 4) ? -1.0f : 1.0f;
#pragma unroll
        for (int k = 0; k < 8; ++k)
#pragma unroll
            for (int e = 0; e < 4; ++e) {
                const float w = swzf<4>(v[k][e]);
                v[k][e] = fmaf(s, v[k][e], w);
            }
    }
    // ---- bit 5: lane xor 8 via ds_swizzle ----
    {
        const float s = (lane & 8) ? -1.0f : 1.0f;
#pragma unroll
        for (int k = 0; k < 8; ++k)
#pragma unroll
            for (int e = 0; e < 4; ++e) {
                const float w = swzf<8>(v[k][e]);
                v[k][e] = fmaf(s, v[k][e], w);
            }
    }

    const float M = 0.022097086912079608f;  // 2^-5.5

#if HAVE_PLSWAP
    // ---- bit 7: swap lane-bit5 <-> pair-bit(k0), butterfly in regs ----
#pragma unroll
    for (int j = 0; j < 4; ++j)
#pragma unroll
        for (int e = 0; e < 4; ++e) {
            pl32_swap(v[2 * j][e], v[2 * j + 1][e]);
            float a = v[2 * j][e], b = v[2 * j + 1][e];
            v[2 * j][e] = a + b; v[2 * j + 1][e] = a - b;
        }
    // ---- bit 6: swap lane-bit4 <-> pair-bit, butterfly in regs ----
#pragma unroll
    for (int j = 0; j < 4; ++j)
#pragma unroll
        for (int e = 0; e < 4; ++e) {
            pl16_swap(v[2 * j][e], v[2 * j + 1][e]);
            float a = v[2 * j][e], b = v[2 * j + 1][e];
            v[2 * j][e] = a + b; v[2 * j + 1][e] = a - b;
        }

    // ---- store: n = k2*1024 + k1*512 + l5*256 + l4*128 + k0*64 + (l&15)*4 + e
    const int lanebase = ((lane >> 5) & 1) * 256 + ((lane >> 4) & 1) * 128 + (lane & 15) * 4;
#pragma unroll
    for (int k = 0; k < 8; ++k) {
        const float mk = (k >= 6) ? -M : M;  // sign depends only on n10&n9 = k2&k1
        const int base = ((k >> 2) & 1) * 1024 + ((k >> 1) & 1) * 512 + (k & 1) * 64;
        f4 t;
        t[0] = v[k][0] * mk; t[1] = v[k][1] * mk;
        t[2] = v[k][2] * mk; t[3] = v[k][3] * mk;
        __builtin_nontemporal_store(t, reinterpret_cast<f4*>(outr + base + lanebase));
    }
#else
    // Fallback: bits 6,7 via shfl_xor, original layout store.
#pragma unroll
    for (int s6 = 4; s6 < 6; ++s6) {
        const int m = 1 << s6;
        const float s = (lane & m) ? -1.0f : 1.0f;
#pragma unroll
        for (int k = 0; k < 8; ++k)
#pragma unroll
            for (int e = 0; e < 4; ++e) {
                const float w = __shfl_xor(v[k][e], m, 64);
                v[k][e] = fmaf(s, v[k][e], w);
            }
    }
#pragma unroll
    for (int k = 0; k < 8; ++k) {
        const float mk = (k >= 6) ? -M : M;
        f4 t;
        t[0] = v[k][0] * mk; t[1] = v[k][1] * mk;
        t[2] = v[k][2] * mk; t[3] = v[k][3] * mk;
        __builtin_nontemporal_store(t, reinterpret_cast<f4*>(outr + 256 * k + 4 * lane));
    }
#endif
}

extern "C" void kernel_launch(void* const* d_in, const int* in_sizes, int n_in,
                              void* d_out, int out_size, void* d_ws, size_t ws_size,
                              hipStream_t stream) {
    const float* x = (const float*)d_in[0];
    float* out = (float*)d_out;
    const int rows = in_sizes[0] / NN;  // 16384
    fwht_sign_kernel<<<dim3(rows / 4), dim3(256), 0, stream>>>(x, out);
}